// Round 13
// baseline (1129.316 us; speedup 1.0000x reference)
//
#include <hip/hip_runtime.h>

#define NB 1024   // boxes
#define NC 151    // classes
#define NCP 152   // padded probs row stride (16B-aligned)
#define DF 4096   // feature dim
typedef unsigned long long u64;

// ---- GEMM + fused softmax: dists = fmap @ W + b; probs = softmax(dists), col0=0 ----
__global__ __launch_bounds__(192) void gemm_sm_kernel(
    const float* __restrict__ fmap, const float* __restrict__ W,
    const float* __restrict__ bias, float* __restrict__ dists,
    float* __restrict__ probs) {
  __shared__ float sf[4 * DF];       // 64 KiB
  __shared__ float sdist[4][NCP];
  __shared__ float smx[4], ssum[4];
  int r0 = blockIdx.x * 4;
  const float4* src = (const float4*)(fmap + (size_t)r0 * DF);
  for (int i = threadIdx.x; i < 4 * (DF / 4); i += 192) {
    int r = i >> 10;       // row 0..3
    int q = i & 1023;      // float4 index within row
    float4 v = src[i];
    sf[(4 * q + 0) * 4 + r] = v.x;
    sf[(4 * q + 1) * 4 + r] = v.y;
    sf[(4 * q + 2) * 4 + r] = v.z;
    sf[(4 * q + 3) * 4 + r] = v.w;
  }
  __syncthreads();
  int c = threadIdx.x;
  if (c < NC) {
    double a0 = 0.0, a1 = 0.0, a2 = 0.0, a3 = 0.0;
    const float* w = W + c;
    const float4* sf4 = (const float4*)sf;
#pragma unroll 8
    for (int d = 0; d < DF; ++d) {
      float4 f = sf4[d];                       // broadcast across wave
      double wv = (double)w[(size_t)d * NC];   // coalesced across threads
      a0 += (double)f.x * wv;
      a1 += (double)f.y * wv;
      a2 += (double)f.z * wv;
      a3 += (double)f.w * wv;
    }
    float b = bias[c];
    float v0 = (float)a0 + b, v1 = (float)a1 + b, v2 = (float)a2 + b, v3 = (float)a3 + b;
    dists[(size_t)(r0 + 0) * NC + c] = v0;
    dists[(size_t)(r0 + 1) * NC + c] = v1;
    dists[(size_t)(r0 + 2) * NC + c] = v2;
    dists[(size_t)(r0 + 3) * NC + c] = v3;
    sdist[0][c] = v0; sdist[1][c] = v1; sdist[2][c] = v2; sdist[3][c] = v3;
  }
  __syncthreads();
  // wave 0 reproduces the original softmax_kernel reduce order exactly
  if (threadIdx.x < 64) {
    int t = threadIdx.x;
#pragma unroll
    for (int r = 0; r < 4; ++r) {
      float v0 = sdist[r][t];
      float v1 = sdist[r][t + 64];
      float v2 = (t + 128 < NC) ? sdist[r][t + 128] : -3.0e38f;
      float m = fmaxf(fmaxf(v0, v1), v2);
      for (int off = 32; off; off >>= 1) m = fmaxf(m, __shfl_down(m, off));
      m = __shfl(m, 0);
      float e0 = expf(v0 - m), e1 = expf(v1 - m);
      float e2 = (t + 128 < NC) ? expf(v2 - m) : 0.0f;
      float s = e0 + e1 + e2;
      for (int off = 32; off; off >>= 1) s += __shfl_down(s, off);
      s = __shfl(s, 0);
      if (t == 0) { smx[r] = m; ssum[r] = s; }
    }
  }
  __syncthreads();
  if (c < NC) {
#pragma unroll
    for (int r = 0; r < 4; ++r) {
      float p = (c == 0) ? 0.0f : (expf(sdist[r][c] - smx[r]) / ssum[r]);
      probs[(size_t)(r0 + r) * NCP + c] = p;
    }
  }
  if (threadIdx.x == 0) {
#pragma unroll
    for (int r = 0; r < 4; ++r) probs[(size_t)(r0 + r) * NCP + NC] = -1.0f;  // pad
  }
}

// ---------------- precompute overlap bitmask: mask[cl][b] = 1024 bits ----------------
__global__ __launch_bounds__(256) void mask_kernel(
    const float* __restrict__ boxes, u64* __restrict__ mask) {
#pragma clang fp contract(off)
  int cl = blockIdx.x >> 4;          // 151 classes
  int bb = (blockIdx.x & 15) * 64;   // 16 b-groups of 64
  __shared__ float4 sbox[NB];
  __shared__ float sarea[NB];
  for (int i = threadIdx.x; i < NB; i += 256) {
    float4 b = *(const float4*)(boxes + ((size_t)i * NC + cl) * 4);
    sbox[i] = b;
    sarea[i] = (b.z - b.x + 1.0f) * (b.w - b.y + 1.0f);
  }
  __syncthreads();
  int wv = threadIdx.x >> 6, lane = threadIdx.x & 63;
  for (int j = 0; j < 16; ++j) {
    int b = bb + wv * 16 + j;
    float4 B = sbox[b];
    float areaB = sarea[b];
    u64 myword = 0;
#pragma unroll
    for (int k = 0; k < 16; ++k) {
      int r = k * 64 + lane;
      float4 R = sbox[r];
      float ix = fminf(B.z, R.z) - fmaxf(B.x, R.x) + 1.0f;
      float iy = fminf(B.w, R.w) - fmaxf(B.y, R.y) + 1.0f;
      ix = fmaxf(ix, 0.0f);
      iy = fmaxf(iy, 0.0f);
      float inter = ix * iy;
      float uni = sarea[r] + areaB - inter;
      float iou = inter / uni;            // IEEE div — must match numpy exactly
      u64 bal = __ballot(iou >= 0.5f);
      if (lane == k) myword = bal;
    }
    if (lane < 16) mask[((size_t)cl * NB + b) * 16 + lane] = myword;
  }
}

// ---------------- greedy commit: FOUR waves, batch-2 per barrier round ----------------
template <int CTRL, int ROWMASK>
__device__ __forceinline__ float dpp_max_step(float v) {
  int x = __float_as_int(v);
  int t = __builtin_amdgcn_update_dpp(x, x, CTRL, ROWMASK, 0xf, false);
  return fmaxf(v, __int_as_float(t));
}

// canonical gfx9 wave64 max reduce; result broadcast via readlane(63)
__device__ __forceinline__ float wave_max(float v) {
  v = dpp_max_step<0x111, 0xf>(v);  // row_shr:1
  v = dpp_max_step<0x112, 0xf>(v);  // row_shr:2
  v = dpp_max_step<0x114, 0xf>(v);  // row_shr:4
  v = dpp_max_step<0x118, 0xf>(v);  // row_shr:8
  v = dpp_max_step<0x142, 0xa>(v);  // row_bcast:15
  v = dpp_max_step<0x143, 0xc>(v);  // row_bcast:31
  return __int_as_float(__builtin_amdgcn_readlane(__float_as_int(v), 63));
}

// scan a read-only probs row with zeroed-class bitmask applied; strict >, first max.
__device__ __forceinline__ void rescan_row(const float* __restrict__ pp,
                                           u64 z0, u64 z1, u64 z2,
                                           float& mo, int& ao) {
  const float4* p4 = (const float4*)pp;
  float m = 0.0f; int a = 0;
#pragma unroll 2
  for (int q = 0; q < NCP / 4; ++q) {
    float4 v = p4[q];
    u64 z = q < 16 ? z0 : (q < 32 ? z1 : z2);
    unsigned bits = (unsigned)(z >> ((q & 15) * 4)) & 0xFu;
    int c0 = q * 4;
    float vx = (bits & 1u) ? 0.0f : v.x;
    float vy = (bits & 2u) ? 0.0f : v.y;
    float vz = (bits & 4u) ? 0.0f : v.z;
    float vw = (bits & 8u) ? 0.0f : v.w;
    if (vx > m) { m = vx; a = c0; }
    if (vy > m) { m = vy; a = c0 + 1; }
    if (vz > m) { m = vz; a = c0 + 2; }
    if (vw > m) { m = vw; a = c0 + 3; }
  }
  mo = m; ao = a;
}

__global__ __launch_bounds__(256, 1) void greedy_kernel(
    const float* __restrict__ probs, const u64* __restrict__ mask,
    float* __restrict__ out_preds) {
  __shared__ u64 smask[NB * 16];      // 128 KB: prefetched argmax-class columns
  __shared__ unsigned pcls[NB];       // 4 KB: class tag of each prefetched column
  __shared__ u64 skey[2][4][2];       // parity-buffered per-wave top-2 keys

  int tid = threadIdx.x;
  int w = tid >> 6, lane = tid & 63;
  int rbase = tid << 2;               // my rows: rbase+0..3
  int widx = tid >> 4;                // my mask word index (row>>6 of my rows)
  int hsh = (tid & 15) << 2;          // shift for my 4 bits within the word

  float rm[4];
  int ra[4], cm[4];
  u64 zb0[4], zb1[4], zb2[4];
  unsigned committed = 0;

  // ---- init: scan my 4 rows; publish initial argmax class ----
#pragma unroll
  for (int r = 0; r < 4; ++r) {
    rescan_row(probs + (size_t)(rbase + r) * NCP, 0, 0, 0, rm[r], ra[r]);
    cm[r] = 0; zb0[r] = 0; zb1[r] = 0; zb2[r] = 0;
    pcls[rbase + r] = (unsigned)ra[r];
  }
  __syncthreads();

  // ---- prefetch 1024 columns (b, ra0[b]) into LDS ----
  for (int j = 0; j < NB; j += 16) {
    int col = j + (tid >> 4);
    int wd = tid & 15;
    unsigned pc = pcls[col];
    smask[(col << 4) | wd] = mask[(((size_t)pc << 10) | (size_t)col) * 16 + wd];
  }
  __syncthreads();

  // sequential-commit state update for one (b, cl, hits); no memory ops
  auto apply = [&](int b, int cl, unsigned hits, unsigned& need) {
    int wi = cl >> 6;
    u64 bmv = 1ull << (cl & 63);
    u64 q0 = (wi == 0) ? bmv : 0, q1 = (wi == 1) ? bmv : 0, q2 = (wi == 2) ? bmv : 0;
    bool meT = (tid == (b >> 2));
    int blo = b & 3;
#pragma unroll
    for (int r = 0; r < 4; ++r) {
      unsigned rb = 1u << r;
      bool hit = (hits & rb) != 0;
      if (r == blo) {
        if (meT) { committed |= rb; rm[r] = -1.0f; cm[r] = cl; hit = false; }
      }
      if (hit) {
        if (committed & rb) {
          if (rm[r] < 0.0f) { rm[r] = 0.0f; ra[r] = cl; }
          else if (cl < ra[r]) ra[r] = cl;
        } else {
          zb0[r] |= q0; zb1[r] |= q1; zb2[r] |= q2;
          if (ra[r] == cl) need |= rb;
        }
      }
    }
  };

  int done = 0, rnd = 0;
  while (done < NB) {
    int par = rnd & 1;
    ++rnd;

    // ---- local top-2 over my 4 rows (ascending, strict >; ties -> smaller row) ----
    float m1 = -2.0f, m2 = -2.0f;
    int a1 = 0, a2 = 0;
#pragma unroll
    for (int r = 0; r < 4; ++r) {
      float v = rm[r];
      int p = (r << 8) | ra[r];
      if (v > m1) { m2 = m1; a2 = a1; m1 = v; a1 = p; }
      else if (v > m2) { m2 = v; a2 = p; }
    }

    // ---- wave top-1 ----
    float wm1 = wave_max(m1);
    u64 ba1 = __ballot(m1 == wm1);
    int wl1 = __ffsll(ba1) - 1;
    int pw1 = __builtin_amdgcn_readlane(a1, wl1);
    // ---- wave top-2 (winner lane contributes its local 2nd) ----
    float c2 = (lane == wl1) ? m2 : m1;
    int p2l = (lane == wl1) ? a2 : a1;
    float wm2 = wave_max(c2);
    u64 ba2 = __ballot(c2 == wm2);
    int wl2 = __ffsll(ba2) - 1;
    int pw2 = __builtin_amdgcn_readlane(p2l, wl2);

    if (lane == 0) {
      int row1 = (w << 8) | (wl1 << 2) | (pw1 >> 8);
      unsigned u1 = __float_as_uint(wm1);
      unsigned s1 = ((int)u1 >= 0) ? (u1 | 0x80000000u) : ~u1;
      skey[par][w][0] = ((u64)s1 << 32) | ((u64)(NB - 1 - row1) << 8) | (unsigned)(pw1 & 0xff);
      int row2 = (w << 8) | (wl2 << 2) | (pw2 >> 8);
      unsigned u2 = __float_as_uint(wm2);
      unsigned s2 = ((int)u2 >= 0) ? (u2 | 0x80000000u) : ~u2;
      skey[par][w][1] = ((u64)s2 << 32) | ((u64)(NB - 1 - row2) << 8) | (unsigned)(pw2 & 0xff);
    }
    __syncthreads();

    // ---- global top-2 of 8 keys (keys unique: rows distinct) ----
    u64 kv[8];
#pragma unroll
    for (int i = 0; i < 8; ++i) kv[i] = skey[par][i >> 1][i & 1];
    u64 kk1 = kv[0];
#pragma unroll
    for (int i = 1; i < 8; ++i) kk1 = kv[i] > kk1 ? kv[i] : kk1;
    u64 kk2 = 0;
#pragma unroll
    for (int i = 0; i < 8; ++i) {
      u64 x = (kv[i] == kk1) ? 0ull : kv[i];
      kk2 = x > kk2 ? x : kk2;
    }

    int b1 = NB - 1 - (int)((kk1 >> 8) & 0x3FFu);
    int cl1 = (int)(kk1 & 0xFFu);
    int b2 = NB - 1 - (int)((kk2 >> 8) & 0x3FFu);
    int cl2 = (int)(kk2 & 0xFFu);
    unsigned su2 = (unsigned)(kk2 >> 32);

    // ---- word loads: per-row hits for b1 & b2 + broadcast check word ----
    unsigned pc1 = pcls[b1], pc2 = pcls[b2];
    bool f1 = ((unsigned)cl1 == pc1), f2 = ((unsigned)cl2 == pc2);
    u64 wordA, wordB, wordChk;
    if (f1 && f2) {          // hot path: three parallel LDS reads
      wordA = smask[(b1 << 4) | widx];
      wordB = smask[(b2 << 4) | widx];
      wordChk = smask[(b1 << 4) | (b2 >> 6)];
    } else {
      wordA = f1 ? smask[(b1 << 4) | widx]
                 : mask[(((size_t)cl1 << 10) | (size_t)b1) * 16 + widx];
      wordB = f2 ? smask[(b2 << 4) | widx]
                 : mask[(((size_t)cl2 << 10) | (size_t)b2) * 16 + widx];
      wordChk = f1 ? smask[(b1 << 4) | (b2 >> 6)]
                   : mask[(((size_t)cl1 << 10) | (size_t)b1) * 16 + (b2 >> 6)];
    }
    unsigned hitsA = (unsigned)(wordA >> hsh) & 0xFu;
    unsigned hitsB = (unsigned)(wordB >> hsh) & 0xFu;

    // ---- commit-2 validity: value2 > 0 strictly, and b2's argmax class survives ----
    bool bitChk = ((wordChk >> (b2 & 63)) & 1ull) != 0;
    bool v2 = (su2 > 0x80000000u) && !(bitChk && (cl1 == cl2)) && (done + 2 <= NB);

    // ---- apply sequentially ----
    unsigned need = 0;
    apply(b1, cl1, hitsA, need);
    if (v2) apply(b2, cl2, hitsB, need);
    done += v2 ? 2 : 1;

    // per-wave rescan branch (no barrier inside)
    if (__ballot(need != 0)) {
#pragma unroll
      for (int r = 0; r < 4; ++r) {
        if (need & (1u << r))
          rescan_row(probs + (size_t)(rbase + r) * NCP,
                     zb0[r], zb1[r], zb2[r], rm[r], ra[r]);
      }
    }
  }

  // ---- write commits ----
#pragma unroll
  for (int r = 0; r < 4; ++r)
    out_preds[rbase + r] = (float)cm[r];
}

// ---------------- host ----------------
extern "C" void kernel_launch(void* const* d_in, const int* in_sizes, int n_in,
                              void* d_out, int out_size, void* d_ws, size_t ws_size,
                              hipStream_t stream) {
  const float* obj_fmap = (const float*)d_in[0];  // [NB, DF]
  const float* W_out    = (const float*)d_in[1];  // [DF, NC]
  const float* b_out    = (const float*)d_in[2];  // [NC]
  const float* boxes    = (const float*)d_in[3];  // [NB, NC, 4]

  float* out_dists = (float*)d_out;            // NB*NC
  float* out_preds = (float*)d_out + NB * NC;  // NB (as float)

  float* probs = (float*)d_ws;                     // NB*NCP floats (622,592 B)
  u64*   mask  = (u64*)(probs + (size_t)NB * NCP); // NC*NB*16 u64 (19.8 MB)

  gemm_sm_kernel<<<NB / 4, 192, 0, stream>>>(obj_fmap, W_out, b_out, out_dists, probs);
  mask_kernel<<<NC * 16, 256, 0, stream>>>(boxes, mask);
  greedy_kernel<<<1, 256, 0, stream>>>(probs, mask, out_preds);
}

// Round 14
// 1002.202 us; speedup vs baseline: 1.1268x; 1.1268x over previous
//
#include <hip/hip_runtime.h>

#define NB 1024   // boxes
#define NC 151    // classes
#define NCP 152   // padded probs row stride (16B-aligned)
#define DF 4096   // feature dim
typedef unsigned long long u64;

// ---- GEMM + fused softmax: dists = fmap @ W + b; probs = softmax(dists), col0=0 ----
// K split in halves across 384 threads; f64 partials combined in fixed order (exact).
__global__ __launch_bounds__(384) void gemm_sm_kernel(
    const float* __restrict__ fmap, const float* __restrict__ W,
    const float* __restrict__ bias, float* __restrict__ dists,
    float* __restrict__ probs) {
  __shared__ float sf[4 * DF];         // 64 KiB
  __shared__ double spart[2][4][NC];   // 9.7 KB f64 partials
  __shared__ float sdist[4][NCP];
  __shared__ float smx[4], ssum[4];
  int r0 = blockIdx.x * 4;
  const float4* src = (const float4*)(fmap + (size_t)r0 * DF);
  for (int i = threadIdx.x; i < 4 * (DF / 4); i += 384) {
    int r = i >> 10;       // row 0..3
    int q = i & 1023;      // float4 index within row
    float4 v = src[i];
    sf[(4 * q + 0) * 4 + r] = v.x;
    sf[(4 * q + 1) * 4 + r] = v.y;
    sf[(4 * q + 2) * 4 + r] = v.z;
    sf[(4 * q + 3) * 4 + r] = v.w;
  }
  __syncthreads();
  {
    int half = (threadIdx.x >= 192) ? 1 : 0;
    int ch = threadIdx.x - half * 192;
    if (ch < NC) {
      double a0 = 0.0, a1 = 0.0, a2 = 0.0, a3 = 0.0;
      const float4* sf4 = (const float4*)sf + half * (DF / 2);
      const float* w = W + ch + (size_t)half * (DF / 2) * NC;
#pragma unroll 8
      for (int d = 0; d < DF / 2; ++d) {
        float4 f = sf4[d];                       // broadcast across wave
        double wv = (double)w[(size_t)d * NC];   // coalesced across threads
        a0 += (double)f.x * wv;
        a1 += (double)f.y * wv;
        a2 += (double)f.z * wv;
        a3 += (double)f.w * wv;
      }
      spart[half][0][ch] = a0;
      spart[half][1][ch] = a1;
      spart[half][2][ch] = a2;
      spart[half][3][ch] = a3;
    }
  }
  __syncthreads();
  int c = threadIdx.x;
  if (c < NC) {
    float b = bias[c];
    float v0 = (float)(spart[0][0][c] + spart[1][0][c]) + b;
    float v1 = (float)(spart[0][1][c] + spart[1][1][c]) + b;
    float v2 = (float)(spart[0][2][c] + spart[1][2][c]) + b;
    float v3 = (float)(spart[0][3][c] + spart[1][3][c]) + b;
    dists[(size_t)(r0 + 0) * NC + c] = v0;
    dists[(size_t)(r0 + 1) * NC + c] = v1;
    dists[(size_t)(r0 + 2) * NC + c] = v2;
    dists[(size_t)(r0 + 3) * NC + c] = v3;
    sdist[0][c] = v0; sdist[1][c] = v1; sdist[2][c] = v2; sdist[3][c] = v3;
  }
  __syncthreads();
  // wave 0 reproduces the original softmax_kernel reduce order exactly
  if (threadIdx.x < 64) {
    int t = threadIdx.x;
#pragma unroll
    for (int r = 0; r < 4; ++r) {
      float v0 = sdist[r][t];
      float v1 = sdist[r][t + 64];
      float v2 = (t + 128 < NC) ? sdist[r][t + 128] : -3.0e38f;
      float m = fmaxf(fmaxf(v0, v1), v2);
      for (int off = 32; off; off >>= 1) m = fmaxf(m, __shfl_down(m, off));
      m = __shfl(m, 0);
      float e0 = expf(v0 - m), e1 = expf(v1 - m);
      float e2 = (t + 128 < NC) ? expf(v2 - m) : 0.0f;
      float s = e0 + e1 + e2;
      for (int off = 32; off; off >>= 1) s += __shfl_down(s, off);
      s = __shfl(s, 0);
      if (t == 0) { smx[r] = m; ssum[r] = s; }
    }
  }
  __syncthreads();
  if (c < NC) {
#pragma unroll
    for (int r = 0; r < 4; ++r) {
      float p = (c == 0) ? 0.0f : (expf(sdist[r][c] - smx[r]) / ssum[r]);
      probs[(size_t)(r0 + r) * NCP + c] = p;
    }
  }
  if (threadIdx.x == 0) {
#pragma unroll
    for (int r = 0; r < 4; ++r) probs[(size_t)(r0 + r) * NCP + NC] = -1.0f;  // pad
  }
}

// ---------------- precompute overlap bitmask: mask[cl][b] = 1024 bits ----------------
__global__ __launch_bounds__(256) void mask_kernel(
    const float* __restrict__ boxes, u64* __restrict__ mask) {
#pragma clang fp contract(off)
  int cl = blockIdx.x >> 4;          // 151 classes
  int bb = (blockIdx.x & 15) * 64;   // 16 b-groups of 64
  __shared__ float4 sbox[NB];
  __shared__ float sarea[NB];
  for (int i = threadIdx.x; i < NB; i += 256) {
    float4 b = *(const float4*)(boxes + ((size_t)i * NC + cl) * 4);
    sbox[i] = b;
    sarea[i] = (b.z - b.x + 1.0f) * (b.w - b.y + 1.0f);
  }
  __syncthreads();
  int wv = threadIdx.x >> 6, lane = threadIdx.x & 63;
  for (int j = 0; j < 16; ++j) {
    int b = bb + wv * 16 + j;
    float4 B = sbox[b];
    float areaB = sarea[b];
    u64 myword = 0;
#pragma unroll
    for (int k = 0; k < 16; ++k) {
      int r = k * 64 + lane;
      float4 R = sbox[r];
      float ix = fminf(B.z, R.z) - fmaxf(B.x, R.x) + 1.0f;
      float iy = fminf(B.w, R.w) - fmaxf(B.y, R.y) + 1.0f;
      ix = fmaxf(ix, 0.0f);
      iy = fmaxf(iy, 0.0f);
      float inter = ix * iy;
      float uni = sarea[r] + areaB - inter;
      float iou = inter / uni;            // IEEE div — must match numpy exactly
      u64 bal = __ballot(iou >= 0.5f);
      if (lane == k) myword = bal;
    }
    if (lane < 16) mask[((size_t)cl * NB + b) * 16 + lane] = myword;
  }
}

// ---------------- greedy commit: FOUR waves, 4 rows/lane, 1 barrier/iter (r12) ----------------
template <int CTRL, int ROWMASK>
__device__ __forceinline__ float dpp_max_step(float v) {
  int x = __float_as_int(v);
  int t = __builtin_amdgcn_update_dpp(x, x, CTRL, ROWMASK, 0xf, false);
  return fmaxf(v, __int_as_float(t));
}

// canonical gfx9 wave64 max reduce; result broadcast via readlane(63)
__device__ __forceinline__ float wave_max(float v) {
  v = dpp_max_step<0x111, 0xf>(v);  // row_shr:1
  v = dpp_max_step<0x112, 0xf>(v);  // row_shr:2
  v = dpp_max_step<0x114, 0xf>(v);  // row_shr:4
  v = dpp_max_step<0x118, 0xf>(v);  // row_shr:8
  v = dpp_max_step<0x142, 0xa>(v);  // row_bcast:15
  v = dpp_max_step<0x143, 0xc>(v);  // row_bcast:31
  return __int_as_float(__builtin_amdgcn_readlane(__float_as_int(v), 63));
}

// scan a read-only probs row with zeroed-class bitmask applied; strict >, first max.
__device__ __forceinline__ void rescan_row(const float* __restrict__ pp,
                                           u64 z0, u64 z1, u64 z2,
                                           float& mo, int& ao) {
  const float4* p4 = (const float4*)pp;
  float m = 0.0f; int a = 0;
#pragma unroll 2
  for (int q = 0; q < NCP / 4; ++q) {
    float4 v = p4[q];
    u64 z = q < 16 ? z0 : (q < 32 ? z1 : z2);
    unsigned bits = (unsigned)(z >> ((q & 15) * 4)) & 0xFu;
    int c0 = q * 4;
    float vx = (bits & 1u) ? 0.0f : v.x;
    float vy = (bits & 2u) ? 0.0f : v.y;
    float vz = (bits & 4u) ? 0.0f : v.z;
    float vw = (bits & 8u) ? 0.0f : v.w;
    if (vx > m) { m = vx; a = c0; }
    if (vy > m) { m = vy; a = c0 + 1; }
    if (vz > m) { m = vz; a = c0 + 2; }
    if (vw > m) { m = vw; a = c0 + 3; }
  }
  mo = m; ao = a;
}

__global__ __launch_bounds__(256, 1) void greedy_kernel(
    const float* __restrict__ probs, const u64* __restrict__ mask,
    float* __restrict__ out_preds) {
  __shared__ u64 smask[NB * 16];      // 128 KB: prefetched argmax-class columns
  __shared__ unsigned pcls[NB];       // 4 KB: class tag of each prefetched column
  __shared__ u64 skey[2][4];          // parity-double-buffered per-wave keys

  int tid = threadIdx.x;
  int w = tid >> 6, lane = tid & 63;
  int rbase = tid << 2;               // my rows: rbase+0..3
  int widx = tid >> 4;                // my mask word index (row>>6 of my rows)
  int hsh = (tid & 15) << 2;          // shift for my 4 bits within the word

  float rm[4];
  int ra[4], cm[4];
  u64 zb0[4], zb1[4], zb2[4];
  unsigned committed = 0;

  // ---- init: scan my 4 rows; publish initial argmax class ----
#pragma unroll
  for (int r = 0; r < 4; ++r) {
    rescan_row(probs + (size_t)(rbase + r) * NCP, 0, 0, 0, rm[r], ra[r]);
    cm[r] = 0; zb0[r] = 0; zb1[r] = 0; zb2[r] = 0;
    pcls[rbase + r] = (unsigned)ra[r];
  }
  __syncthreads();

  // ---- prefetch 1024 columns (b, ra0[b]) into LDS ----
  for (int j = 0; j < NB; j += 16) {
    int col = j + (tid >> 4);
    int wd = tid & 15;
    unsigned pc = pcls[col];
    smask[(col << 4) | wd] = mask[(((size_t)pc << 10) | (size_t)col) * 16 + wd];
  }
  __syncthreads();

  for (int it = 0; it < NB; ++it) {
    int par = it & 1;

    // ---- local argmax over my 4 rows (ascending, strict > => smallest row on tie) ----
    float bv = rm[0];
    int bp = ra[0];                  // packed (r<<8)|ra
#pragma unroll
    for (int r = 1; r < 4; ++r) {
      int p = (r << 8) | ra[r];
      bool t = rm[r] > bv;
      bv = t ? rm[r] : bv;
      bp = t ? p : bp;
    }

    // ---- per-wave winner ----
    float wmax = wave_max(bv);
    u64 ball = __ballot(bv == wmax);
    int wl = __ffsll(ball) - 1;      // smallest lane = smallest row in wave
    int pw = __builtin_amdgcn_readlane(bp, wl);
    int gw = (w << 8) | (wl << 2) | (pw >> 8);   // wave-winner row
    int clw = pw & 0xff;
    unsigned ub = __float_as_uint(wmax);
    unsigned su = ((int)ub >= 0) ? (ub | 0x80000000u) : ~ub;  // monotone u32 of float
    u64 key = ((u64)su << 32) | ((u64)(NB - 1 - gw) << 8) | (unsigned)clw;
    if (lane == 0) skey[par][w] = key;
    __syncthreads();

    // ---- global winner (all waves redundantly; broadcast LDS reads) ----
    u64 k0 = skey[par][0], k1 = skey[par][1], k2 = skey[par][2], k3 = skey[par][3];
    u64 ka = k0 > k1 ? k0 : k1;
    u64 kb = k2 > k3 ? k2 : k3;
    u64 kk = ka > kb ? ka : kb;
    int b = NB - 1 - (int)((kk >> 8) & 0x3FFu);
    int cl = (int)(kk & 0xFFu);
    // endgame guard: all rows at -1 -> reference flat argmax picks (0,0)
    if ((unsigned)(kk >> 32) < 0x80000000u) cl = 0;

    // ---- mask word: issue LDS read immediately; rare uniform fallback to global ----
    u64 word = smask[(b << 4) | widx];
    unsigned pc = pcls[b];
    if ((unsigned)cl != pc) {
      word = mask[(((size_t)cl << 10) | (size_t)b) * 16 + widx];
    }
    unsigned hits = (unsigned)(word >> hsh) & 0xFu;

    // per-word bit of class cl (uniform), branch-free
    int wi = cl >> 6;
    u64 bmv = 1ull << (cl & 63);
    u64 m0 = (wi == 0) ? bmv : 0, m1 = (wi == 1) ? bmv : 0, m2 = (wi == 2) ? bmv : 0;

    bool meT = (tid == (b >> 2));
    int blo = b & 3;

    // ---- update my 4 rows ----
    unsigned need = 0;
#pragma unroll
    for (int r = 0; r < 4; ++r) {
      unsigned rb = 1u << r;
      bool hit = (hits & rb) != 0;
      if (r == blo) {                // scalar compare (blo uniform)
        if (meT) { committed |= rb; rm[r] = -1.0f; cm[r] = cl; hit = false; }
      }
      if (hit) {
        if (committed & rb) {
          // committed row: -1 everywhere except re-zeroed cols (0)
          if (rm[r] < 0.0f) { rm[r] = 0.0f; ra[r] = cl; }
          else if (cl < ra[r]) ra[r] = cl;
        } else {
          zb0[r] |= m0; zb1[r] |= m1; zb2[r] |= m2;
          if (ra[r] == cl) need |= rb;   // max may have dropped
        }
      }
    }
    // per-wave rescan branch (no barrier inside -> waves independent)
    if (__ballot(need != 0)) {
#pragma unroll
      for (int r = 0; r < 4; ++r) {
        if (need & (1u << r))
          rescan_row(probs + (size_t)(rbase + r) * NCP,
                     zb0[r], zb1[r], zb2[r], rm[r], ra[r]);
      }
    }
  }

  // ---- write commits ----
#pragma unroll
  for (int r = 0; r < 4; ++r)
    out_preds[rbase + r] = (float)cm[r];
}

// ---------------- host ----------------
extern "C" void kernel_launch(void* const* d_in, const int* in_sizes, int n_in,
                              void* d_out, int out_size, void* d_ws, size_t ws_size,
                              hipStream_t stream) {
  const float* obj_fmap = (const float*)d_in[0];  // [NB, DF]
  const float* W_out    = (const float*)d_in[1];  // [DF, NC]
  const float* b_out    = (const float*)d_in[2];  // [NC]
  const float* boxes    = (const float*)d_in[3];  // [NB, NC, 4]

  float* out_dists = (float*)d_out;            // NB*NC
  float* out_preds = (float*)d_out + NB * NC;  // NB (as float)

  float* probs = (float*)d_ws;                     // NB*NCP floats (622,592 B)
  u64*   mask  = (u64*)(probs + (size_t)NB * NCP); // NC*NB*16 u64 (19.8 MB)

  gemm_sm_kernel<<<NB / 4, 384, 0, stream>>>(obj_fmap, W_out, b_out, out_dists, probs);
  mask_kernel<<<NC * 16, 256, 0, stream>>>(boxes, mask);
  greedy_kernel<<<1, 256, 0, stream>>>(probs, mask, out_preds);
}

// Round 15
// 1000.695 us; speedup vs baseline: 1.1285x; 1.0015x over previous
//
#include <hip/hip_runtime.h>

#define NB 1024   // boxes
#define NC 151    // classes
#define NCP 152   // padded probs row stride (16B-aligned)
#define DF 4096   // feature dim
#define GEMM_BLOCKS (NB / 4)      // 256
#define MASK_BLOCKS (NC * 16)     // 2416
typedef unsigned long long u64;

// ---- fused prep: blocks [0,256) = GEMM+softmax ; blocks [256,2672) = overlap mask ----
// Independent work fused into one dispatch so it runs concurrently across CUs.
__global__ __launch_bounds__(384) void prep_kernel(
    const float* __restrict__ fmap, const float* __restrict__ W,
    const float* __restrict__ bias, const float* __restrict__ boxes,
    float* __restrict__ dists, float* __restrict__ probs,
    u64* __restrict__ mask) {
  __shared__ __align__(16) char smem[77696];  // union arena (75.9 KB)

  if (blockIdx.x < GEMM_BLOCKS) {
    // ======== GEMM + fused softmax (identical math to r14) ========
    float* sf     = (float*)smem;                          // 4*DF floats (65536 B)
    double* spart = (double*)(smem + 65536);               // 2*4*NC doubles (9664 B)
    float* sdist  = (float*)(smem + 65536 + 9664);         // 4*NCP floats (2432 B)
    float* smx    = (float*)(smem + 65536 + 9664 + 2432);  // 4 floats
    float* ssum   = smx + 4;

    int r0 = blockIdx.x * 4;
    const float4* src = (const float4*)(fmap + (size_t)r0 * DF);
    for (int i = threadIdx.x; i < 4 * (DF / 4); i += 384) {
      int r = i >> 10;       // row 0..3
      int q = i & 1023;      // float4 index within row
      float4 v = src[i];
      sf[(4 * q + 0) * 4 + r] = v.x;
      sf[(4 * q + 1) * 4 + r] = v.y;
      sf[(4 * q + 2) * 4 + r] = v.z;
      sf[(4 * q + 3) * 4 + r] = v.w;
    }
    __syncthreads();
    {
      int half = (threadIdx.x >= 192) ? 1 : 0;
      int ch = threadIdx.x - half * 192;
      if (ch < NC) {
        double a0 = 0.0, a1 = 0.0, a2 = 0.0, a3 = 0.0;
        const float4* sf4 = (const float4*)sf + half * (DF / 2);
        const float* w = W + ch + (size_t)half * (DF / 2) * NC;
#pragma unroll 8
        for (int d = 0; d < DF / 2; ++d) {
          float4 f = sf4[d];                       // broadcast across wave
          double wv = (double)w[(size_t)d * NC];   // coalesced across threads
          a0 += (double)f.x * wv;
          a1 += (double)f.y * wv;
          a2 += (double)f.z * wv;
          a3 += (double)f.w * wv;
        }
        spart[(half * 4 + 0) * NC + ch] = a0;
        spart[(half * 4 + 1) * NC + ch] = a1;
        spart[(half * 4 + 2) * NC + ch] = a2;
        spart[(half * 4 + 3) * NC + ch] = a3;
      }
    }
    __syncthreads();
    int c = threadIdx.x;
    if (c < NC) {
      float b = bias[c];
      float v0 = (float)(spart[0 * NC + c] + spart[4 * NC + c]) + b;
      float v1 = (float)(spart[1 * NC + c] + spart[5 * NC + c]) + b;
      float v2 = (float)(spart[2 * NC + c] + spart[6 * NC + c]) + b;
      float v3 = (float)(spart[3 * NC + c] + spart[7 * NC + c]) + b;
      dists[(size_t)(r0 + 0) * NC + c] = v0;
      dists[(size_t)(r0 + 1) * NC + c] = v1;
      dists[(size_t)(r0 + 2) * NC + c] = v2;
      dists[(size_t)(r0 + 3) * NC + c] = v3;
      sdist[0 * NCP + c] = v0; sdist[1 * NCP + c] = v1;
      sdist[2 * NCP + c] = v2; sdist[3 * NCP + c] = v3;
    }
    __syncthreads();
    // wave 0 reproduces the original softmax reduce order exactly
    if (threadIdx.x < 64) {
      int t = threadIdx.x;
#pragma unroll
      for (int r = 0; r < 4; ++r) {
        float v0 = sdist[r * NCP + t];
        float v1 = sdist[r * NCP + t + 64];
        float v2 = (t + 128 < NC) ? sdist[r * NCP + t + 128] : -3.0e38f;
        float m = fmaxf(fmaxf(v0, v1), v2);
        for (int off = 32; off; off >>= 1) m = fmaxf(m, __shfl_down(m, off));
        m = __shfl(m, 0);
        float e0 = expf(v0 - m), e1 = expf(v1 - m);
        float e2 = (t + 128 < NC) ? expf(v2 - m) : 0.0f;
        float s = e0 + e1 + e2;
        for (int off = 32; off; off >>= 1) s += __shfl_down(s, off);
        s = __shfl(s, 0);
        if (t == 0) { smx[r] = m; ssum[r] = s; }
      }
    }
    __syncthreads();
    if (c < NC) {
#pragma unroll
      for (int r = 0; r < 4; ++r) {
        float p = (c == 0) ? 0.0f : (expf(sdist[r * NCP + c] - smx[r]) / ssum[r]);
        probs[(size_t)(r0 + r) * NCP + c] = p;
      }
    }
    if (threadIdx.x == 0) {
#pragma unroll
      for (int r = 0; r < 4; ++r) probs[(size_t)(r0 + r) * NCP + NC] = -1.0f;  // pad
    }
  } else {
    // ======== overlap bitmask (identical math to r14) ========
#pragma clang fp contract(off)
    float4* sbox = (float4*)smem;            // 16 KB
    float* sarea = (float*)(smem + 16384);   // 4 KB
    int mb = blockIdx.x - GEMM_BLOCKS;
    int cl = mb >> 4;          // 151 classes
    int bb = (mb & 15) * 64;   // 16 b-groups of 64
    for (int i = threadIdx.x; i < NB; i += 384) {
      float4 b = *(const float4*)(boxes + ((size_t)i * NC + cl) * 4);
      sbox[i] = b;
      sarea[i] = (b.z - b.x + 1.0f) * (b.w - b.y + 1.0f);
    }
    __syncthreads();           // all 6 waves participate
    int wv = threadIdx.x >> 6, lane = threadIdx.x & 63;
    if (wv < 4) {              // waves 4-5 idle (no barrier below)
      for (int j = 0; j < 16; ++j) {
        int b = bb + wv * 16 + j;
        float4 B = sbox[b];
        float areaB = sarea[b];
        u64 myword = 0;
#pragma unroll
        for (int k = 0; k < 16; ++k) {
          int r = k * 64 + lane;
          float4 R = sbox[r];
          float ix = fminf(B.z, R.z) - fmaxf(B.x, R.x) + 1.0f;
          float iy = fminf(B.w, R.w) - fmaxf(B.y, R.y) + 1.0f;
          ix = fmaxf(ix, 0.0f);
          iy = fmaxf(iy, 0.0f);
          float inter = ix * iy;
          float uni = sarea[r] + areaB - inter;
          float iou = inter / uni;            // IEEE div — must match numpy exactly
          u64 bal = __ballot(iou >= 0.5f);
          if (lane == k) myword = bal;
        }
        if (lane < 16) mask[((size_t)cl * NB + b) * 16 + lane] = myword;
      }
    }
  }
}

// ---------------- greedy commit: FOUR waves, 4 rows/lane, 1 barrier/iter (r14) ----------------
template <int CTRL, int ROWMASK>
__device__ __forceinline__ float dpp_max_step(float v) {
  int x = __float_as_int(v);
  int t = __builtin_amdgcn_update_dpp(x, x, CTRL, ROWMASK, 0xf, false);
  return fmaxf(v, __int_as_float(t));
}

// canonical gfx9 wave64 max reduce; result broadcast via readlane(63)
__device__ __forceinline__ float wave_max(float v) {
  v = dpp_max_step<0x111, 0xf>(v);  // row_shr:1
  v = dpp_max_step<0x112, 0xf>(v);  // row_shr:2
  v = dpp_max_step<0x114, 0xf>(v);  // row_shr:4
  v = dpp_max_step<0x118, 0xf>(v);  // row_shr:8
  v = dpp_max_step<0x142, 0xa>(v);  // row_bcast:15
  v = dpp_max_step<0x143, 0xc>(v);  // row_bcast:31
  return __int_as_float(__builtin_amdgcn_readlane(__float_as_int(v), 63));
}

// scan a read-only probs row with zeroed-class bitmask applied; strict >, first max.
__device__ __forceinline__ void rescan_row(const float* __restrict__ pp,
                                           u64 z0, u64 z1, u64 z2,
                                           float& mo, int& ao) {
  const float4* p4 = (const float4*)pp;
  float m = 0.0f; int a = 0;
#pragma unroll 2
  for (int q = 0; q < NCP / 4; ++q) {
    float4 v = p4[q];
    u64 z = q < 16 ? z0 : (q < 32 ? z1 : z2);
    unsigned bits = (unsigned)(z >> ((q & 15) * 4)) & 0xFu;
    int c0 = q * 4;
    float vx = (bits & 1u) ? 0.0f : v.x;
    float vy = (bits & 2u) ? 0.0f : v.y;
    float vz = (bits & 4u) ? 0.0f : v.z;
    float vw = (bits & 8u) ? 0.0f : v.w;
    if (vx > m) { m = vx; a = c0; }
    if (vy > m) { m = vy; a = c0 + 1; }
    if (vz > m) { m = vz; a = c0 + 2; }
    if (vw > m) { m = vw; a = c0 + 3; }
  }
  mo = m; ao = a;
}

__global__ __launch_bounds__(256, 1) void greedy_kernel(
    const float* __restrict__ probs, const u64* __restrict__ mask,
    float* __restrict__ out_preds) {
  __shared__ u64 smask[NB * 16];      // 128 KB: prefetched argmax-class columns
  __shared__ unsigned pcls[NB];       // 4 KB: class tag of each prefetched column
  __shared__ u64 skey[2][4];          // parity-double-buffered per-wave keys

  int tid = threadIdx.x;
  int w = tid >> 6, lane = tid & 63;
  int rbase = tid << 2;               // my rows: rbase+0..3
  int widx = tid >> 4;                // my mask word index (row>>6 of my rows)
  int hsh = (tid & 15) << 2;          // shift for my 4 bits within the word

  float rm[4];
  int ra[4], cm[4];
  u64 zb0[4], zb1[4], zb2[4];
  unsigned committed = 0;

  // ---- init: scan my 4 rows; publish initial argmax class ----
#pragma unroll
  for (int r = 0; r < 4; ++r) {
    rescan_row(probs + (size_t)(rbase + r) * NCP, 0, 0, 0, rm[r], ra[r]);
    cm[r] = 0; zb0[r] = 0; zb1[r] = 0; zb2[r] = 0;
    pcls[rbase + r] = (unsigned)ra[r];
  }
  __syncthreads();

  // ---- prefetch 1024 columns (b, ra0[b]) into LDS ----
  for (int j = 0; j < NB; j += 16) {
    int col = j + (tid >> 4);
    int wd = tid & 15;
    unsigned pc = pcls[col];
    smask[(col << 4) | wd] = mask[(((size_t)pc << 10) | (size_t)col) * 16 + wd];
  }
  __syncthreads();

  for (int it = 0; it < NB; ++it) {
    int par = it & 1;

    // ---- local argmax over my 4 rows (ascending, strict > => smallest row on tie) ----
    float bv = rm[0];
    int bp = ra[0];                  // packed (r<<8)|ra
#pragma unroll
    for (int r = 1; r < 4; ++r) {
      int p = (r << 8) | ra[r];
      bool t = rm[r] > bv;
      bv = t ? rm[r] : bv;
      bp = t ? p : bp;
    }

    // ---- per-wave winner ----
    float wmax = wave_max(bv);
    u64 ball = __ballot(bv == wmax);
    int wl = __ffsll(ball) - 1;      // smallest lane = smallest row in wave
    int pw = __builtin_amdgcn_readlane(bp, wl);
    int gw = (w << 8) | (wl << 2) | (pw >> 8);   // wave-winner row
    int clw = pw & 0xff;
    unsigned ub = __float_as_uint(wmax);
    unsigned su = ((int)ub >= 0) ? (ub | 0x80000000u) : ~ub;  // monotone u32 of float
    u64 key = ((u64)su << 32) | ((u64)(NB - 1 - gw) << 8) | (unsigned)clw;
    if (lane == 0) skey[par][w] = key;
    __syncthreads();

    // ---- global winner (all waves redundantly; broadcast LDS reads) ----
    u64 k0 = skey[par][0], k1 = skey[par][1], k2 = skey[par][2], k3 = skey[par][3];
    u64 ka = k0 > k1 ? k0 : k1;
    u64 kb = k2 > k3 ? k2 : k3;
    u64 kk = ka > kb ? ka : kb;
    int b = NB - 1 - (int)((kk >> 8) & 0x3FFu);
    int cl = (int)(kk & 0xFFu);
    // endgame guard: all rows at -1 -> reference flat argmax picks (0,0)
    if ((unsigned)(kk >> 32) < 0x80000000u) cl = 0;

    // ---- mask word: issue LDS read immediately; rare uniform fallback to global ----
    u64 word = smask[(b << 4) | widx];
    unsigned pc = pcls[b];
    if ((unsigned)cl != pc) {
      word = mask[(((size_t)cl << 10) | (size_t)b) * 16 + widx];
    }
    unsigned hits = (unsigned)(word >> hsh) & 0xFu;

    // per-word bit of class cl (uniform), branch-free
    int wi = cl >> 6;
    u64 bmv = 1ull << (cl & 63);
    u64 m0 = (wi == 0) ? bmv : 0, m1 = (wi == 1) ? bmv : 0, m2 = (wi == 2) ? bmv : 0;

    bool meT = (tid == (b >> 2));
    int blo = b & 3;

    // ---- update my 4 rows ----
    unsigned need = 0;
#pragma unroll
    for (int r = 0; r < 4; ++r) {
      unsigned rb = 1u << r;
      bool hit = (hits & rb) != 0;
      if (r == blo) {                // scalar compare (blo uniform)
        if (meT) { committed |= rb; rm[r] = -1.0f; cm[r] = cl; hit = false; }
      }
      if (hit) {
        if (committed & rb) {
          // committed row: -1 everywhere except re-zeroed cols (0)
          if (rm[r] < 0.0f) { rm[r] = 0.0f; ra[r] = cl; }
          else if (cl < ra[r]) ra[r] = cl;
        } else {
          zb0[r] |= m0; zb1[r] |= m1; zb2[r] |= m2;
          if (ra[r] == cl) need |= rb;   // max may have dropped
        }
      }
    }
    // per-wave rescan branch (no barrier inside -> waves independent)
    if (__ballot(need != 0)) {
#pragma unroll
      for (int r = 0; r < 4; ++r) {
        if (need & (1u << r))
          rescan_row(probs + (size_t)(rbase + r) * NCP,
                     zb0[r], zb1[r], zb2[r], rm[r], ra[r]);
      }
    }
  }

  // ---- write commits ----
#pragma unroll
  for (int r = 0; r < 4; ++r)
    out_preds[rbase + r] = (float)cm[r];
}

// ---------------- host ----------------
extern "C" void kernel_launch(void* const* d_in, const int* in_sizes, int n_in,
                              void* d_out, int out_size, void* d_ws, size_t ws_size,
                              hipStream_t stream) {
  const float* obj_fmap = (const float*)d_in[0];  // [NB, DF]
  const float* W_out    = (const float*)d_in[1];  // [DF, NC]
  const float* b_out    = (const float*)d_in[2];  // [NC]
  const float* boxes    = (const float*)d_in[3];  // [NB, NC, 4]

  float* out_dists = (float*)d_out;            // NB*NC
  float* out_preds = (float*)d_out + NB * NC;  // NB (as float)

  float* probs = (float*)d_ws;                     // NB*NCP floats (622,592 B)
  u64*   mask  = (u64*)(probs + (size_t)NB * NCP); // NC*NB*16 u64 (19.8 MB)

  prep_kernel<<<GEMM_BLOCKS + MASK_BLOCKS, 384, 0, stream>>>(
      obj_fmap, W_out, b_out, boxes, out_dists, probs, mask);
  greedy_kernel<<<1, 256, 0, stream>>>(probs, mask, out_preds);
}